// Round 15
// baseline (63.059 us; speedup 1.0000x reference)
//
#include <hip/hip_runtime.h>
#include <math.h>

#define B_ 1024
#define D_ 2048
#define M_ 32
#define H_ 32

#define DPB 8         // d per block = 8 waves, one d per wave
#define BPB 128       // b per block = 8 b-tiles of 16 rows
#define NT  8         // b-tiles
#define OPAD 9        // out-gather row pad

typedef _Float16 f16x8 __attribute__((ext_vector_type(8)));
typedef __fp16   h16x2 __attribute__((ext_vector_type(2)));
typedef __fp16   h16x4 __attribute__((ext_vector_type(4)));
typedef __fp16   h16x8 __attribute__((ext_vector_type(8)));
typedef float    f32x4 __attribute__((ext_vector_type(4)));

// Abramowitz & Stegun 7.1.26, |err| <= 1.5e-7 absolute. Uses hw rcp + exp.
__device__ __forceinline__ float fast_erff(float x) {
    float ax = fabsf(x);
    float t  = __builtin_amdgcn_rcpf(1.0f + 0.3275911f * ax);
    float p  = 1.061405429f;
    p = p * t - 1.453152027f;
    p = p * t + 1.421413741f;
    p = p * t - 0.284496736f;
    p = p * t + 0.254829592f;
    float e = __expf(-ax * ax);
    float r = 1.0f - p * t * e;
    return copysignf(r, x);
}

__device__ __forceinline__ float gelu_exact(float x) {
    return 0.5f * x * (1.0f + fast_erff(x * 0.70710678118f));
}

// tanh(x) = 1 - 2/(exp(2x)+1); exp(inf)->inf->rcp->0 gives +/-1 at extremes.
__device__ __forceinline__ float fast_tanhf(float x) {
    return 1.0f - 2.0f * __builtin_amdgcn_rcpf(__expf(2.0f * x) + 1.0f);
}

// Packed fp32->fp16 (RTZ): 4 v_cvt_pkrtz instead of 8 scalar cvts.
__device__ __forceinline__ f16x8 cvt8(const float4 a, const float4 b) {
    const h16x2 h0 = __builtin_amdgcn_cvt_pkrtz(a.x, a.y);
    const h16x2 h1 = __builtin_amdgcn_cvt_pkrtz(a.z, a.w);
    const h16x2 h2 = __builtin_amdgcn_cvt_pkrtz(b.x, b.y);
    const h16x2 h3 = __builtin_amdgcn_cvt_pkrtz(b.z, b.w);
    const h16x4 lo = __builtin_shufflevector(h0, h1, 0, 1, 2, 3);
    const h16x4 hi = __builtin_shufflevector(h2, h3, 0, 1, 2, 3);
    const h16x8 v  = __builtin_shufflevector(lo, hi, 0, 1, 2, 3, 4, 5, 6, 7);
    return __builtin_bit_cast(f16x8, v);
}

// Async global->LDS DMA, 16 B per lane: dest = uniform LDS base + lane*16.
typedef __attribute__((address_space(1))) const unsigned int ga_u32;
typedef __attribute__((address_space(3))) unsigned int ls_u32;
__device__ __forceinline__ void gload_lds16(const float* g, float* l) {
    __builtin_amdgcn_global_load_lds((ga_u32*)g, (ls_u32*)l, 16, 0, 0);
}

__global__ __launch_bounds__(512)
void nlm_kernel(const float* __restrict__ pre,
                const float* __restrict__ w1,
                const float* __restrict__ b1,
                const float* __restrict__ w_out,
                const float* __restrict__ b_out,
                float* __restrict__ out) {
    __shared__ float pbuf[2][16 * 256];   // 2 x 16 KB: 16 b-rows x 1 KB, linear
    __shared__ float obuf[BPB * OPAD];    // 4.6 KB

    const int tid  = threadIdx.x;
    const int lane = tid & 63;
    const int w    = tid >> 6;          // 0..7: wave -> one d; also stages rows 2w,2w+1
    const int c16  = lane & 15;         // A-row h / B-col b
    const int g    = lane >> 4;         // 0..3: k-group (k = g*8 + j)

    // XCD-aware bijective swizzle (r11): contiguous runs per XCD.
    const int linear = ((blockIdx.x & 7) << 8) | (blockIdx.x >> 3);
    const int dt = linear & 255;
    const int bt = linear >> 8;
    const int d0 = dt * DPB;
    const int b0 = bt * BPB;

    const int du = __builtin_amdgcn_readfirstlane(d0 + w);

    // ---- A operand: W[h = c16 (+16)][k = g*8 + j], contiguous 32 B ----
    const float* wbase = w1 + (size_t)du * (H_ * M_);
    const f16x8 wa0 = cvt8(*(const float4*)(wbase + c16 * M_ + g * 8),
                           *(const float4*)(wbase + c16 * M_ + g * 8 + 4));
    const f16x8 wa1 = cvt8(*(const float4*)(wbase + (c16 + 16) * M_ + g * 8),
                           *(const float4*)(wbase + (c16 + 16) * M_ + g * 8 + 4));

    // ---- per-lane bias / w_out quads for C-rows h = g*4 + r (and +16) ----
    const f32x4 b1q0 = *(const f32x4*)(b1    + (size_t)du * H_ + g * 4);
    const f32x4 b1q1 = *(const f32x4*)(b1    + (size_t)du * H_ + g * 4 + 16);
    const f32x4 woq0 = *(const f32x4*)(w_out + (size_t)du * H_ + g * 4);
    const f32x4 woq1 = *(const f32x4*)(w_out + (size_t)du * H_ + g * 4 + 16);
    const float bo   = b_out[du];

// Stage tile T into pbuf[BUFI]: wave w DMAs b-rows 2w, 2w+1 (1 KB each,
// lane-contiguous 16-B pieces -> copy-style coalescing, 8 lines/inst).
#define STAGE(T, BUFI)                                                          \
    {                                                                           \
        const float* g0_ = pre + ((size_t)(b0 + (T) * 16 + 2 * w) * D_ + d0) * M_; \
        const float* g1_ = g0_ + (size_t)D_ * M_;                               \
        gload_lds16(g0_ + lane * 4, &pbuf[BUFI][(2 * w) * 256]);                \
        gload_lds16(g1_ + lane * 4, &pbuf[BUFI][(2 * w + 1) * 256]);            \
    }

    // ---- prologue: stage tile 0 ----
    STAGE(0, 0)
    __syncthreads();

#pragma unroll
    for (int t = 0; t < NT; ++t) {
        const int cur = t & 1;

        // issue next tile's DMA first (T14 issue-early; in flight under compute)
        if (t + 1 < NT) {
            if ((t + 1) & 1) { STAGE(t + 1, 1) } else { STAGE(t + 1, 0) }
        }

        // ---- B-fragment from LDS: row c16, float4s (w*8 + 2g, +1) ----
        const float4* prd = reinterpret_cast<const float4*>(&pbuf[cur][0]);
        const float4 lo = prd[c16 * 64 + w * 8 + g * 2];
        const float4 hi = prd[c16 * 64 + w * 8 + g * 2 + 1];
        const f16x8 pf = cvt8(lo, hi);

        f32x4 acc0 = b1q0, acc1 = b1q1;
        acc0 = __builtin_amdgcn_mfma_f32_16x16x32_f16(wa0, pf, acc0, 0, 0, 0);
        acc1 = __builtin_amdgcn_mfma_f32_16x16x32_f16(wa1, pf, acc1, 0, 0, 0);

        float p = 0.f;
#pragma unroll
        for (int r = 0; r < 4; ++r) {
            p = fmaf(gelu_exact(acc0[r]), woq0[r], p);
            p = fmaf(gelu_exact(acc1[r]), woq1[r], p);
        }
        p += __shfl_xor(p, 16, 64);
        p += __shfl_xor(p, 32, 64);

        if (lane < 16)
            obuf[(t * 16 + c16) * OPAD + w] = fast_tanhf(p + bo);

        // barrier: drains this iter's DMA (next tile ready) + guards buf reuse
        __syncthreads();
    }

    // ---- flush: 256 threads store one float4; full-line-friendly (r11-proven) ----
    if (tid < 2 * BPB) {
        const int r  = tid >> 1;            // 0..127
        const int cc = (tid & 1) * 4;       // 0 or 4
        float4 o;
        o.x = obuf[r * OPAD + cc + 0];
        o.y = obuf[r * OPAD + cc + 1];
        o.z = obuf[r * OPAD + cc + 2];
        o.w = obuf[r * OPAD + cc + 3];
        *reinterpret_cast<float4*>(out + (size_t)(b0 + r) * D_ + d0 + cc) = o;
    }
}

extern "C" void kernel_launch(void* const* d_in, const int* in_sizes, int n_in,
                              void* d_out, int out_size, void* d_ws, size_t ws_size,
                              hipStream_t stream) {
    const float* pre   = (const float*)d_in[0];
    const float* w1    = (const float*)d_in[1];
    const float* b1    = (const float*)d_in[2];
    const float* w_out = (const float*)d_in[3];
    const float* b_out = (const float*)d_in[4];
    float* out = (float*)d_out;

    const int grid = (D_ / DPB) * (B_ / BPB);   // 256 * 8 = 2048
    nlm_kernel<<<dim3(grid), dim3(512), 0, stream>>>(pre, w1, b1, w_out, b_out, out);
}

// Round 16
// 56.568 us; speedup vs baseline: 1.1147x; 1.1147x over previous
//
#include <hip/hip_runtime.h>
#include <math.h>

#define B_ 1024
#define D_ 2048
#define M_ 32
#define H_ 32

#define DPB 8         // d per block = 8 waves, one d per wave
#define BPB 128       // b per block = 8 b-tiles of 16 rows
#define OPAD 9        // out-gather row pad

typedef _Float16 f16x8 __attribute__((ext_vector_type(8)));
typedef __fp16   h16x2 __attribute__((ext_vector_type(2)));
typedef __fp16   h16x4 __attribute__((ext_vector_type(4)));
typedef __fp16   h16x8 __attribute__((ext_vector_type(8)));
typedef float    f32x4 __attribute__((ext_vector_type(4)));

// Abramowitz & Stegun 7.1.26, |err| <= 1.5e-7 absolute. Uses hw rcp + exp.
__device__ __forceinline__ float fast_erff(float x) {
    float ax = fabsf(x);
    float t  = __builtin_amdgcn_rcpf(1.0f + 0.3275911f * ax);
    float p  = 1.061405429f;
    p = p * t - 1.453152027f;
    p = p * t + 1.421413741f;
    p = p * t - 0.284496736f;
    p = p * t + 0.254829592f;
    float e = __expf(-ax * ax);
    float r = 1.0f - p * t * e;
    return copysignf(r, x);
}

__device__ __forceinline__ float gelu_exact(float x) {
    return 0.5f * x * (1.0f + fast_erff(x * 0.70710678118f));
}

// tanh(x) = 1 - 2/(exp(2x)+1); exp(inf)->inf->rcp->0 gives +/-1 at extremes.
__device__ __forceinline__ float fast_tanhf(float x) {
    return 1.0f - 2.0f * __builtin_amdgcn_rcpf(__expf(2.0f * x) + 1.0f);
}

// Packed fp32->fp16 (RTZ): 4 v_cvt_pkrtz instead of 8 scalar cvts.
__device__ __forceinline__ f16x8 cvt8(const float4 a, const float4 b) {
    const h16x2 h0 = __builtin_amdgcn_cvt_pkrtz(a.x, a.y);
    const h16x2 h1 = __builtin_amdgcn_cvt_pkrtz(a.z, a.w);
    const h16x2 h2 = __builtin_amdgcn_cvt_pkrtz(b.x, b.y);
    const h16x2 h3 = __builtin_amdgcn_cvt_pkrtz(b.z, b.w);
    const h16x4 lo = __builtin_shufflevector(h0, h1, 0, 1, 2, 3);
    const h16x4 hi = __builtin_shufflevector(h2, h3, 0, 1, 2, 3);
    const h16x8 v  = __builtin_shufflevector(lo, hi, 0, 1, 2, 3, 4, 5, 6, 7);
    return __builtin_bit_cast(f16x8, v);
}

// Load b-tile T's B-fragment halves (2 x float4, 32 B per lane, contiguous).
#define LOADT(T, RA, RB)                                                       \
    {                                                                          \
        const float* pa_ = pbase + (size_t)(T) * 16 * D_ * M_;                 \
        RA = *reinterpret_cast<const float4*>(pa_);                            \
        RB = *reinterpret_cast<const float4*>(pa_ + 4);                        \
    }

// Process b-tile T from registers RA/RB (r12-proven body).
#define PROCT(T, RA, RB)                                                       \
    {                                                                          \
        const f16x8 pf = cvt8(RA, RB);                                         \
        f32x4 acc0 = b1q0, acc1 = b1q1;                                        \
        acc0 = __builtin_amdgcn_mfma_f32_16x16x32_f16(wa0, pf, acc0, 0, 0, 0); \
        acc1 = __builtin_amdgcn_mfma_f32_16x16x32_f16(wa1, pf, acc1, 0, 0, 0); \
        float p = 0.f;                                                         \
        _Pragma("unroll")                                                      \
        for (int r = 0; r < 4; ++r) {                                          \
            p = fmaf(gelu_exact(acc0[r]), woq0[r], p);                         \
            p = fmaf(gelu_exact(acc1[r]), woq1[r], p);                         \
        }                                                                      \
        p += __shfl_xor(p, 16, 64);                                            \
        p += __shfl_xor(p, 32, 64);                                            \
        if (lane < 16)                                                         \
            obuf[((T) * 16 + c16) * OPAD + w] = fast_tanhf(p + bo);            \
    }

__global__ __launch_bounds__(512)
void nlm_kernel(const float* __restrict__ pre,
                const float* __restrict__ w1,
                const float* __restrict__ b1,
                const float* __restrict__ w_out,
                const float* __restrict__ b_out,
                float* __restrict__ out) {
    __shared__ float obuf[BPB * OPAD];   // 4.6 KB

    const int tid  = threadIdx.x;
    const int lane = tid & 63;
    const int w    = tid >> 6;          // 0..7: wave -> one d
    const int c16  = lane & 15;         // A-row h / B-col b
    const int g    = lane >> 4;         // 0..3: k-group (k = g*8 + j)

    // XCD-aware bijective swizzle (r11): contiguous runs per XCD.
    const int linear = ((blockIdx.x & 7) << 8) | (blockIdx.x >> 3);
    const int dt = linear & 255;
    const int bt = linear >> 8;
    const int d0 = dt * DPB;
    const int b0 = bt * BPB;

    const int du = __builtin_amdgcn_readfirstlane(d0 + w);

    // ---- A operand: W[h = c16 (+16)][k = g*8 + j], contiguous 32 B ----
    const float* wbase = w1 + (size_t)du * (H_ * M_);
    const f16x8 wa0 = cvt8(*(const float4*)(wbase + c16 * M_ + g * 8),
                           *(const float4*)(wbase + c16 * M_ + g * 8 + 4));
    const f16x8 wa1 = cvt8(*(const float4*)(wbase + (c16 + 16) * M_ + g * 8),
                           *(const float4*)(wbase + (c16 + 16) * M_ + g * 8 + 4));

    // ---- per-lane bias / w_out quads for C-rows h = g*4 + r (and +16) ----
    const f32x4 b1q0 = *(const f32x4*)(b1    + (size_t)du * H_ + g * 4);
    const f32x4 b1q1 = *(const f32x4*)(b1    + (size_t)du * H_ + g * 4 + 16);
    const f32x4 woq0 = *(const f32x4*)(w_out + (size_t)du * H_ + g * 4);
    const f32x4 woq1 = *(const f32x4*)(w_out + (size_t)du * H_ + g * 4 + 16);
    const float bo   = b_out[du];

    // B operand base: P[k = g*8+j][b = b0 + t*16 + c16] = pre[b][du][k]
    const float* pbase = pre + ((size_t)(b0 + c16) * D_ + du) * M_ + g * 8;

    // ---- depth-2 software pipeline: every load in flight across 2 epilogues ----
    float4 xA, xB, yA, yB;
    LOADT(0, xA, xB)
    LOADT(1, yA, yB)
    PROCT(0, xA, xB)  LOADT(2, xA, xB)
    PROCT(1, yA, yB)  LOADT(3, yA, yB)
    PROCT(2, xA, xB)  LOADT(4, xA, xB)
    PROCT(3, yA, yB)  LOADT(5, yA, yB)
    PROCT(4, xA, xB)  LOADT(6, xA, xB)
    PROCT(5, yA, yB)  LOADT(7, yA, yB)
    PROCT(6, xA, xB)
    PROCT(7, yA, yB)

    __syncthreads();

    // ---- flush: 256 threads store one float4; full-line-friendly (r11-proven) ----
    if (tid < 2 * BPB) {
        const int r  = tid >> 1;            // 0..127
        const int cc = (tid & 1) * 4;       // 0 or 4
        float4 o;
        o.x = obuf[r * OPAD + cc + 0];
        o.y = obuf[r * OPAD + cc + 1];
        o.z = obuf[r * OPAD + cc + 2];
        o.w = obuf[r * OPAD + cc + 3];
        *reinterpret_cast<float4*>(out + (size_t)(b0 + r) * D_ + d0 + cc) = o;
    }
}

extern "C" void kernel_launch(void* const* d_in, const int* in_sizes, int n_in,
                              void* d_out, int out_size, void* d_ws, size_t ws_size,
                              hipStream_t stream) {
    const float* pre   = (const float*)d_in[0];
    const float* w1    = (const float*)d_in[1];
    const float* b1    = (const float*)d_in[2];
    const float* w_out = (const float*)d_in[3];
    const float* b_out = (const float*)d_in[4];
    float* out = (float*)d_out;

    const int grid = (D_ / DPB) * (B_ / BPB);   // 256 * 8 = 2048
    nlm_kernel<<<dim3(grid), dim3(512), 0, stream>>>(pre, w1, b1, w_out, b_out, out);
}